// Round 3
// baseline (116.959 us; speedup 1.0000x reference)
//
#include <hip/hip_runtime.h>
#include <math.h>

#define RES_W 256
#define RES_H 256
#define MAX_SAMPLES 384
#define TF_RES 128

__global__ __launch_bounds__(64) void raycast_kernel(
    const float* __restrict__ vol,    // [256,256,256] x-major: idx = (x<<16)+(y<<8)+z
    const float* __restrict__ tf,     // [128,4]
    const float* __restrict__ cam_p,  // [3]
    const int*   __restrict__ sr_p,   // [1]
    float* __restrict__ out)          // [256,256,5]  idx = (w*256+h)*5+c
{
    #pragma clang fp contract(off)

    __shared__ float4 tf_s[TF_RES];
    const int tid = threadIdx.y * 8 + threadIdx.x;
    const float4* tf4 = (const float4*)tf;
    tf_s[tid]      = tf4[tid];
    tf_s[tid + 64] = tf4[tid + 64];
    __syncthreads();

    const int h = blockIdx.x * 8 + threadIdx.x;   // H index (v axis)
    const int w = blockIdx.y * 8 + threadIdx.y;   // W index (u axis)

    const float cx = cam_p[0], cy = cam_p[1], cz = cam_p[2];
    const int   sr_i = sr_p[0];
    const float srf = (float)sr_i;

    // ---- camera basis, fp32, numpy op order, no FMA ----
    // fwd = (-cam)/norm(-cam); norm = sqrt(((x^2)+(y^2))+(z^2))
    float nx = -cx, ny = -cy, nz = -cz;
    float fl = __fsqrt_rn((nx*nx + ny*ny) + nz*nz);
    float fx = nx / fl, fy = ny / fl, fz = nz / fl;
    // right = normalize(cross(fwd,(0,1,0))) = normalize((-fz, 0, fx))
    float rxu = 0.0f - fz;           // fy*0 - fz*1
    float rzu = fx;                  // fx*1 - fy*0
    float rl = __fsqrt_rn((rxu*rxu + 0.0f) + rzu*rzu);
    float rx = rxu / rl, rz = rzu / rl;
    // up = cross(right, fwd), ry = 0
    float ux = 0.0f - rz*fy;         // ry*fz - rz*fy
    float uy = rz*fx - rx*fz;
    float uz = rx*fy;                // rx*fy - ry*fx

    // tan(radians(30)/2) as fp32, correctly rounded
    const float ang32 = (float)((30.0 * 0.017453292519943295) * 0.5);
    const float tan_half = (float)tan((double)ang32);

    // u = (((w+0.5)/256)*2 - 1)*tan*aspect(=1);  v likewise from h
    float uu = ((((float)w + 0.5f) / 256.0f) * 2.0f - 1.0f) * tan_half; // *1.0f exact
    float vv = ((((float)h + 0.5f) / 256.0f) * 2.0f - 1.0f) * tan_half;

    // dirs = (fwd + u*right) + v*up, then /norm
    float dx = (fx + uu*rx) + vv*ux;
    float dy = (fy + 0.0f ) + vv*uy;     // u*ry = u*0 = 0; fy + 0.0f == fy
    float dz = (fz + uu*rz) + vv*uz;
    float dl = __fsqrt_rn((dx*dx + dy*dy) + dz*dz);
    dx = dx / dl; dy = dy / dl; dz = dz / dl;

    // inv = 1/dirs; t_lo = (-1-cam)*inv; t_hi = (1-cam)*inv
    float ivx = 1.0f/dx, ivy = 1.0f/dy, ivz = 1.0f/dz;
    float tlx = (-1.0f - cx)*ivx, thx = (1.0f - cx)*ivx;
    float tly = (-1.0f - cy)*ivy, thy = (1.0f - cy)*ivy;
    float tlz = (-1.0f - cz)*ivz, thz = (1.0f - cz)*ivz;
    float tmin = fmaxf(fmaxf(fminf(tlx,thx), fminf(tly,thy)), fminf(tlz,thz));
    float tmax = fminf(fminf(fmaxf(tlx,thx), fmaxf(tly,thy)), fmaxf(tlz,thz));
    bool hit = (tmax >= 0.0f) && (tmin <= tmax);

    float entry = fmaxf(tmin, 0.1f);
    float dist  = hit ? fmaxf(tmax - entry, 0.0f) : 0.0f;
    float nsf   = fminf(fmaxf(ceilf(((dist * 0.5f) * 256.0f) * srf), 1.0f), 384.0f);
    int   ns    = (int)nsf;
    float step  = dist / nsf;

    float rgb_r = 0.0f, rgb_g = 0.0f, rgb_b = 0.0f;
    float acc = 0.0f;
    float Texcl = 1.0f;
    float depth = 1.0f;
    bool  found = false;

    if (hit) {
        for (int k = 0; k < ns; ++k) {
            float t  = entry + ((float)k + 0.5f) * step;
            // pos = cam + t*dirs ; tex = ((pos*0.5)+0.5)*255 ; clip to [0,255]
            float px = (cx + t*dx);
            float py = (cy + t*dy);
            float pz = (cz + t*dz);
            px = ((px * 0.5f) + 0.5f) * 255.0f;
            py = ((py * 0.5f) + 0.5f) * 255.0f;
            pz = ((pz * 0.5f) + 0.5f) * 255.0f;
            px = fminf(fmaxf(px, 0.0f), 255.0f);
            py = fminf(fmaxf(py, 0.0f), 255.0f);
            pz = fminf(fmaxf(pz, 0.0f), 255.0f);
            int x0 = (int)floorf(px), y0 = (int)floorf(py), z0 = (int)floorf(pz);
            float ffx = px - (float)x0;
            float ffy = py - (float)y0;
            float ffz = pz - (float)z0;
            int x1 = min(x0 + 1, 255);
            int y1 = min(y0 + 1, 255);
            int z1 = min(z0 + 1, 255);

            int bx0 = x0 << 16, bx1 = x1 << 16;
            int by0 = y0 << 8,  by1 = y1 << 8;
            float c000 = vol[bx0 + by0 + z0];
            float c100 = vol[bx1 + by0 + z0];
            float c010 = vol[bx0 + by1 + z0];
            float c110 = vol[bx1 + by1 + z0];
            float c001 = vol[bx0 + by0 + z1];
            float c101 = vol[bx1 + by0 + z1];
            float c011 = vol[bx0 + by1 + z1];
            float c111 = vol[bx1 + by1 + z1];

            float omx = 1.0f - ffx, omy = 1.0f - ffy, omz = 1.0f - ffz;
            float c00 = c000*omx + c100*ffx;
            float c10 = c010*omx + c110*ffx;
            float c01 = c001*omx + c101*ffx;
            float c11 = c011*omx + c111*ffx;
            float c0  = c00*omy + c10*ffy;
            float c1  = c01*omy + c11*ffy;
            float intensity = c0*omz + c1*ffz;

            // tf_lookup
            float xi = fminf(fmaxf(intensity, 0.0f), 1.0f) * 127.0f;
            int lo  = (int)floorf(xi);
            int hi2 = min(lo + 1, 127);
            float tfr = xi - (float)lo;
            float omt = 1.0f - tfr;
            float4 ca = tf_s[lo];
            float4 cb = tf_s[hi2];
            float cr  = ca.x*omt + cb.x*tfr;
            float cg  = ca.y*omt + cb.y*tfr;
            float cbb = ca.z*omt + cb.z*tfr;
            float a   = ca.w*omt + cb.w*tfr;

            // opacity correction: a = 1 - (1-a)**(1/sr); exact identity path for sr==1
            if (sr_i == 1) {
                a = 1.0f - (1.0f - a);          // double rounding, as numpy does
            } else {
                a = 1.0f - powf(1.0f - a, 1.0f / srf);
            }

            float one_m = 1.0f - a;             // re-rounded, as reference's one_m
            float wgt = Texcl * a;
            rgb_r += wgt * cr;
            rgb_g += wgt * cg;
            rgb_b += wgt * cbb;
            acc   += wgt;
            if (!found && a > 1e-3f) {
                found = true;
                depth = (t - 0.1f) / 99.9f;     // (t-NEAR)/(FAR-NEAR)
            }
            Texcl = Texcl * one_m;
            if (found && Texcl < 1e-7f) break;  // residual error <= Texcl
        }
    }

    {
        int oi = (w * RES_H + h) * 5;
        out[oi + 0] = rgb_r;
        out[oi + 1] = rgb_g;
        out[oi + 2] = rgb_b;
        out[oi + 3] = acc;
        out[oi + 4] = depth;
    }
}

extern "C" void kernel_launch(void* const* d_in, const int* in_sizes, int n_in,
                              void* d_out, int out_size, void* d_ws, size_t ws_size,
                              hipStream_t stream) {
    const float* vol = (const float*)d_in[0];
    const float* tf  = (const float*)d_in[1];
    const float* cam = (const float*)d_in[2];
    const int*   sr  = (const int*)d_in[3];
    float* out = (float*)d_out;

    dim3 block(8, 8, 1);
    dim3 grid(RES_H / 8, RES_W / 8, 1);
    raycast_kernel<<<grid, block, 0, stream>>>(vol, tf, cam, sr, out);
}

// Round 4
// 113.035 us; speedup vs baseline: 1.0347x; 1.0347x over previous
//
#include <hip/hip_runtime.h>
#include <math.h>

#define RES_W 256
#define RES_H 256
#define MAX_SAMPLES 384
#define TF_RES 128

__global__ __launch_bounds__(64) void raycast_kernel(
    const float* __restrict__ vol,    // [256,256,256] x-major: idx = (x<<16)+(y<<8)+z
    const float* __restrict__ tf,     // [128,4]
    const float* __restrict__ cam_p,  // [3]
    const int*   __restrict__ sr_p,   // [1]
    float* __restrict__ out)          // [256,256,5]  idx = (w*256+h)*5+c
{
    #pragma clang fp contract(off)

    __shared__ float4 tf_s[TF_RES];
    const int tid = (int)threadIdx.x;          // 0..63
    const float4* tf4 = (const float4*)tf;
    tf_s[tid]      = tf4[tid];
    tf_s[tid + 64] = tf4[tid + 64];
    __syncthreads();

    // XCD-aware tile swizzle: dispatch round-robin sends block b to XCD b%8.
    // Give XCD k a contiguous slab of 128 tiles (4 consecutive w-tile rows)
    // so its ~0.5 MB volume footprint stays resident in its own 4 MiB L2.
    const int b    = (int)blockIdx.x;          // 0..1023
    const int tile = (b % 8) * 128 + (b / 8);  // 0..1023
    const int tile_h = tile % 32;
    const int tile_w = tile / 32;
    const int h = tile_h * 8 + (tid % 8);      // H index (v axis)
    const int w = tile_w * 8 + (tid / 8);      // W index (u axis)

    const float cx = cam_p[0], cy = cam_p[1], cz = cam_p[2];
    const int   sr_i = sr_p[0];
    const float srf = (float)sr_i;

    // ---- camera basis, fp32, numpy op order, no FMA ----
    float nx = -cx, ny = -cy, nz = -cz;
    float fl = __fsqrt_rn((nx*nx + ny*ny) + nz*nz);
    float fx = nx / fl, fy = ny / fl, fz = nz / fl;
    float rxu = 0.0f - fz;
    float rzu = fx;
    float rl = __fsqrt_rn((rxu*rxu + 0.0f) + rzu*rzu);
    float rx = rxu / rl, rz = rzu / rl;
    float ux = 0.0f - rz*fy;
    float uy = rz*fx - rx*fz;
    float uz = rx*fy;

    const float ang32 = (float)((30.0 * 0.017453292519943295) * 0.5);
    const float tan_half = (float)tan((double)ang32);

    float uu = ((((float)w + 0.5f) / 256.0f) * 2.0f - 1.0f) * tan_half;
    float vv = ((((float)h + 0.5f) / 256.0f) * 2.0f - 1.0f) * tan_half;

    float dx = (fx + uu*rx) + vv*ux;
    float dy = (fy + 0.0f ) + vv*uy;
    float dz = (fz + uu*rz) + vv*uz;
    float dl = __fsqrt_rn((dx*dx + dy*dy) + dz*dz);
    dx = dx / dl; dy = dy / dl; dz = dz / dl;

    float ivx = 1.0f/dx, ivy = 1.0f/dy, ivz = 1.0f/dz;
    float tlx = (-1.0f - cx)*ivx, thx = (1.0f - cx)*ivx;
    float tly = (-1.0f - cy)*ivy, thy = (1.0f - cy)*ivy;
    float tlz = (-1.0f - cz)*ivz, thz = (1.0f - cz)*ivz;
    float tmin = fmaxf(fmaxf(fminf(tlx,thx), fminf(tly,thy)), fminf(tlz,thz));
    float tmax = fminf(fminf(fmaxf(tlx,thx), fmaxf(tly,thy)), fmaxf(tlz,thz));
    bool hit = (tmax >= 0.0f) && (tmin <= tmax);

    float entry = fmaxf(tmin, 0.1f);
    float dist  = hit ? fmaxf(tmax - entry, 0.0f) : 0.0f;
    float nsf   = fminf(fmaxf(ceilf(((dist * 0.5f) * 256.0f) * srf), 1.0f), 384.0f);
    int   ns    = (int)nsf;
    float step  = dist / nsf;

    float rgb_r = 0.0f, rgb_g = 0.0f, rgb_b = 0.0f;
    float acc = 0.0f;
    float Texcl = 1.0f;
    float depth = 1.0f;
    bool  found = false;

    if (hit) {
        for (int k0 = 0; k0 < ns; k0 += 4) {
            // ---- phase A: positions + 32 independent gathers ----
            float t_[4], val[4][8], ffx_[4], ffy_[4], ffz_[4];
            #pragma unroll
            for (int j = 0; j < 4; ++j) {
                float t  = entry + ((float)(k0 + j) + 0.5f) * step;
                t_[j] = t;
                float px = (cx + t*dx);
                float py = (cy + t*dy);
                float pz = (cz + t*dz);
                px = ((px * 0.5f) + 0.5f) * 255.0f;
                py = ((py * 0.5f) + 0.5f) * 255.0f;
                pz = ((pz * 0.5f) + 0.5f) * 255.0f;
                px = fminf(fmaxf(px, 0.0f), 255.0f);
                py = fminf(fmaxf(py, 0.0f), 255.0f);
                pz = fminf(fmaxf(pz, 0.0f), 255.0f);
                int x0 = (int)floorf(px), y0 = (int)floorf(py), z0 = (int)floorf(pz);
                ffx_[j] = px - (float)x0;
                ffy_[j] = py - (float)y0;
                ffz_[j] = pz - (float)z0;
                int x1 = min(x0 + 1, 255);
                int y1 = min(y0 + 1, 255);
                int z1 = min(z0 + 1, 255);
                int bx0 = x0 << 16, bx1 = x1 << 16;
                int by0 = y0 << 8,  by1 = y1 << 8;
                val[j][0] = vol[bx0 + by0 + z0];
                val[j][1] = vol[bx1 + by0 + z0];
                val[j][2] = vol[bx0 + by1 + z0];
                val[j][3] = vol[bx1 + by1 + z0];
                val[j][4] = vol[bx0 + by0 + z1];
                val[j][5] = vol[bx1 + by0 + z1];
                val[j][6] = vol[bx0 + by1 + z1];
                val[j][7] = vol[bx1 + by1 + z1];
            }
            // ---- phase B: intensities + batched TF LDS reads ----
            float tfr_[4];
            float4 ca_[4], cb_[4];
            #pragma unroll
            for (int j = 0; j < 4; ++j) {
                float omx = 1.0f - ffx_[j], omy = 1.0f - ffy_[j], omz = 1.0f - ffz_[j];
                float c00 = val[j][0]*omx + val[j][1]*ffx_[j];
                float c10 = val[j][2]*omx + val[j][3]*ffx_[j];
                float c01 = val[j][4]*omx + val[j][5]*ffx_[j];
                float c11 = val[j][6]*omx + val[j][7]*ffx_[j];
                float c0  = c00*omy + c10*ffy_[j];
                float c1  = c01*omy + c11*ffy_[j];
                float intensity = c0*omz + c1*ffz_[j];
                float xi = fminf(fmaxf(intensity, 0.0f), 1.0f) * 127.0f;
                int lo  = (int)floorf(xi);
                int hi2 = min(lo + 1, 127);
                tfr_[j] = xi - (float)lo;
                ca_[j] = tf_s[lo];
                cb_[j] = tf_s[hi2];
            }
            // ---- phase C: ordered compositing (bit-identical to reference) ----
            #pragma unroll
            for (int j = 0; j < 4; ++j) {
                if (k0 + j < ns) {
                    float tfr = tfr_[j];
                    float omt = 1.0f - tfr;
                    float cr  = ca_[j].x*omt + cb_[j].x*tfr;
                    float cg  = ca_[j].y*omt + cb_[j].y*tfr;
                    float cbb = ca_[j].z*omt + cb_[j].z*tfr;
                    float a   = ca_[j].w*omt + cb_[j].w*tfr;
                    if (sr_i == 1) {
                        a = 1.0f - (1.0f - a);
                    } else {
                        a = 1.0f - powf(1.0f - a, 1.0f / srf);
                    }
                    float one_m = 1.0f - a;
                    float wgt = Texcl * a;
                    rgb_r += wgt * cr;
                    rgb_g += wgt * cg;
                    rgb_b += wgt * cbb;
                    acc   += wgt;
                    if (!found && a > 1e-3f) {
                        found = true;
                        depth = (t_[j] - 0.1f) / 99.9f;
                    }
                    Texcl = Texcl * one_m;
                }
            }
            if (found && Texcl < 1e-7f) break;   // residual error <= Texcl
        }
    }

    {
        int oi = (w * RES_H + h) * 5;
        out[oi + 0] = rgb_r;
        out[oi + 1] = rgb_g;
        out[oi + 2] = rgb_b;
        out[oi + 3] = acc;
        out[oi + 4] = depth;
    }
}

extern "C" void kernel_launch(void* const* d_in, const int* in_sizes, int n_in,
                              void* d_out, int out_size, void* d_ws, size_t ws_size,
                              hipStream_t stream) {
    const float* vol = (const float*)d_in[0];
    const float* tf  = (const float*)d_in[1];
    const float* cam = (const float*)d_in[2];
    const int*   sr  = (const int*)d_in[3];
    float* out = (float*)d_out;

    raycast_kernel<<<dim3(1024), dim3(64), 0, stream>>>(vol, tf, cam, sr, out);
}